// Round 14
// baseline (170.247 us; speedup 1.0000x reference)
//
#include <hip/hip_runtime.h>
#include <hip/hip_bf16.h>
#include <stdint.h>

#define TSEQ 2048
#define DMODEL 1024

typedef __attribute__((ext_vector_type(8))) short bf16x8;
typedef __attribute__((ext_vector_type(4))) float f32x4;
typedef __attribute__((ext_vector_type(16))) float f32x16;
typedef __attribute__((ext_vector_type(2))) int int2v;

union Frag { bf16x8 v; uint4 q; };

__device__ __forceinline__ uint16_t f2bfu(float f) {
  uint32_t u = __builtin_bit_cast(uint32_t, f);
  u += 0x7fffu + ((u >> 16) & 1u);
  return (uint16_t)(u >> 16);
}

__device__ __forceinline__ uint32_t pk2bf(float a, float b) {
  return ((uint32_t)f2bfu(b) << 16) | f2bfu(a);
}

// hardware packed f32->bf16 (RTNE), low half = first operand
__device__ __forceinline__ uint32_t cvtpk(float a, float b) {
  uint32_t r;
  asm("v_cvt_pk_bf16_f32 %0, %1, %2" : "=v"(r) : "v"(a), "v"(b));
  return r;
}

// Swap halves between two regs: on return a = {a.lo31, b.lo31}, b = {a.hi31, b.hi31}
__device__ __forceinline__ void plane32swap(uint32_t& a, uint32_t& b) {
#if __has_builtin(__builtin_amdgcn_permlane32_swap)
  int2v r = __builtin_amdgcn_permlane32_swap((int)a, (int)b, false, false);
  a = (uint32_t)r[0];
  b = (uint32_t)r[1];
#else
  const uint32_t sa = (uint32_t)__shfl_xor((int)a, 32);
  const uint32_t sb = (uint32_t)__shfl_xor((int)b, 32);
  const bool hi = (threadIdx.x & 63) >= 32;
  const uint32_t na = hi ? sb : a;
  const uint32_t nb = hi ? b : sa;
  a = na;
  b = nb;
#endif
}

__device__ __forceinline__ float fexp2(float x) {
#if __has_builtin(__builtin_amdgcn_exp2f)
  return __builtin_amdgcn_exp2f(x);
#else
  return exp2f(x);
#endif
}

__device__ __forceinline__ void gload_lds16(const void* g, void* l) {
  __builtin_amdgcn_global_load_lds(
      (const __attribute__((address_space(1))) void*)g,
      (__attribute__((address_space(3))) void*)l, 16, 0, 0);
}

// ---------------- prep kernels ----------------

__global__ __launch_bounds__(256) void cvt_x_kernel(const float* __restrict__ x,
                                                    uint16_t* __restrict__ xb, int n4) {
  int i = blockIdx.x * 256 + threadIdx.x;
  if (i >= n4) return;
  float4 v = ((const float4*)x)[i];
  ushort4 o;
  o.x = f2bfu(v.x); o.y = f2bfu(v.y); o.z = f2bfu(v.z); o.w = f2bfu(v.w);
  ((ushort4*)xb)[i] = o;
}

// dst[n][k] = src[k][n], fp32 -> bf16.  Wq gets 0.125*log2(e) folded in (exp2 softmax).
__global__ __launch_bounds__(256) void cvt_w_kernel(const float* __restrict__ Wq,
    const float* __restrict__ Wk, const float* __restrict__ Wv, const float* __restrict__ Wo,
    uint16_t* __restrict__ Wqkvt, uint16_t* __restrict__ Wot) {
  const float* src = (blockIdx.z == 0) ? Wq : (blockIdx.z == 1) ? Wk
                   : (blockIdx.z == 2) ? Wv : Wo;
  uint16_t* dst = (blockIdx.z < 3) ? (Wqkvt + (size_t)blockIdx.z * DMODEL * DMODEL) : Wot;
  const float wscale = (blockIdx.z == 0) ? 0.125f * 1.4426950408889634f : 1.0f;
  __shared__ float tile[32][33];
  const int x0 = blockIdx.x * 32, y0 = blockIdx.y * 32;
  for (int ii = 0; ii < 4; ii++) {
    int i = threadIdx.y + ii * 8;
    tile[i][threadIdx.x] = src[(size_t)(y0 + i) * DMODEL + x0 + threadIdx.x];
  }
  __syncthreads();
  for (int ii = 0; ii < 4; ii++) {
    int i = threadIdx.y + ii * 8;
    dst[(size_t)(x0 + i) * DMODEL + y0 + threadIdx.x] = f2bfu(tile[threadIdx.x][i] * wscale);
  }
}

// ---- shared staging helper: 256 rows x 64 K (32KB), 4 x 512 threads ----
__device__ __forceinline__ void stage256(const char* Gb, int kb, char* ldsT, int tid) {
#pragma unroll
  for (int r = 0; r < 4; ++r) {
    const int u = tid + r * 512;
    const int row = u >> 3;
    const int sc = ((u & 7) * 16) ^ ((row & 7) << 4);
    gload_lds16(Gb + (size_t)row * 2048 + kb + sc, ldsT + u * 16);
  }
}

// ======== 256x256 GEMM core: per-wave 128x64 (m201 geometry) ========

__device__ __forceinline__ void gemm256sq_core(const char* Ab, const char* Bb,
                                               char* lds,  // 131072 bytes
                                               f32x4 (&acc)[8][4]) {
  const int tid = threadIdx.x;
  const int lane = tid & 63;
  const int w = tid >> 6;
  const int lr = lane & 15, lg = lane >> 4;
  const int wmb = (w >> 2) * 128;  // 0,128
  const int wnb = (w & 3) * 64;    // 0,64,128,192
  char* const A0 = lds;
  char* const A1 = lds + 32768;
  char* const B0 = lds + 65536;
  char* const B1 = lds + 98304;

#pragma unroll
  for (int i = 0; i < 8; i++)
#pragma unroll
    for (int j = 0; j < 4; j++) acc[i][j] = (f32x4){0.f, 0.f, 0.f, 0.f};

  stage256(Ab, 0, A0, tid);
  stage256(Bb, 0, B0, tid);
  for (int t = 0; t < 16; ++t) {
    const char* At = (t & 1) ? A1 : A0;
    const char* Bt = (t & 1) ? B1 : B0;
    char* nA = (t & 1) ? A0 : A1;
    char* nB = (t & 1) ? B0 : B1;
    if (t + 1 < 16) {
      stage256(Ab, (t + 1) * 128, nA, tid);                // A(t+1) in flight
      asm volatile("s_waitcnt vmcnt(4)" ::: "memory");     // tile t fully landed
    } else {
      asm volatile("s_waitcnt vmcnt(0)" ::: "memory");
    }
    __builtin_amdgcn_s_barrier();                          // buffer t ready
    __builtin_amdgcn_sched_barrier(0);

    Frag bf0[4], bf1[4];
#pragma unroll
    for (int ni = 0; ni < 4; ni++) {
      const int row = wnb + ni * 16 + lr;
      const int swz = (row & 7) << 4;
      bf0[ni].q = *(const uint4*)(Bt + row * 128 + ((lg * 16) ^ swz));
      bf1[ni].q = *(const uint4*)(Bt + row * 128 + ((64 + lg * 16) ^ swz));
    }
#pragma unroll
    for (int ph = 0; ph < 4; ph++) {
      Frag a0[2], a1[2];
#pragma unroll
      for (int i = 0; i < 2; i++) {
        const int row = wmb + (2 * ph + i) * 16 + lr;
        const int swz = (row & 7) << 4;
        a0[i].q = *(const uint4*)(At + row * 128 + ((lg * 16) ^ swz));
        a1[i].q = *(const uint4*)(At + row * 128 + ((64 + lg * 16) ^ swz));
      }
      __builtin_amdgcn_s_setprio(1);
#pragma unroll
      for (int i = 0; i < 2; i++) {
        const int mi = 2 * ph + i;
#pragma unroll
        for (int ni = 0; ni < 4; ni++) {
          acc[mi][ni] = __builtin_amdgcn_mfma_f32_16x16x32_bf16(a0[i].v, bf0[ni].v,
                                                                acc[mi][ni], 0, 0, 0);
          acc[mi][ni] = __builtin_amdgcn_mfma_f32_16x16x32_bf16(a1[i].v, bf1[ni].v,
                                                                acc[mi][ni], 0, 0, 0);
        }
      }
      __builtin_amdgcn_s_setprio(0);
      if (ph == 0 && t + 1 < 16) stage256(Bb, (t + 1) * 128, nB, tid);  // B(t+1)
    }
    __builtin_amdgcn_s_barrier();                          // buffer t consumed
  }
}

// ---------------- Q/K projection GEMM: 256x256, grid 256 = 1 round ----------------

__global__ __launch_bounds__(512, 2) void gemm_qk_kernel(const uint16_t* __restrict__ Xb,
    const uint16_t* __restrict__ Wt, uint16_t* __restrict__ Qo,
    uint16_t* __restrict__ Ko) {
  __shared__ __align__(16) char lds[131072];
  const int m0 = (blockIdx.x & 31) * 256;
  const int n0 = (blockIdx.x >> 5) * 256;
  f32x4 acc[8][4];
  gemm256sq_core((const char*)Xb + (size_t)m0 * 2048, (const char*)Wt + (size_t)n0 * 2048,
                 lds, acc);

  const int tid = threadIdx.x, w = tid >> 6, lane = tid & 63;
  const int lr = lane & 15, lg = lane >> 4;
  const int wmb = (w >> 2) * 128, wnb = (w & 3) * 64;
#pragma unroll
  for (int mi = 0; mi < 8; mi++)
#pragma unroll
    for (int ni = 0; ni < 4; ni++) {
      const int col = n0 + wnb + ni * 16 + lr;
      const int p = col >> 10, c = col & 1023, h = c >> 6, d = c & 63;
#pragma unroll
      for (int r = 0; r < 4; r++) {
        const int row = m0 + wmb + mi * 16 + 4 * lg + r;
        const int bb = row >> 11, t = row & 2047;
        const int bh = bb * 16 + h;
        const uint16_t val = f2bfu(acc[mi][ni][r]);
        if (p == 0) Qo[((size_t)bh * TSEQ + t) * 64 + d] = val;
        else        Ko[((size_t)bh * TSEQ + t) * 64 + d] = val;
      }
    }
}

// ======== 256x128 GEMM core (round-9 verified) — used by V and out proj ========

__device__ __forceinline__ void g8_stage_p1(const char* Ab, int kb, char* ldsA, int tid) {
#pragma unroll
  for (int r = 0; r < 3; ++r) {
    const int u = tid + r * 512;
    const int row = u >> 3;
    const int sc = ((u & 7) * 16) ^ ((row & 7) << 4);
    gload_lds16(Ab + (size_t)row * 2048 + kb + sc, ldsA + u * 16);
  }
}

__device__ __forceinline__ void g8_stage_p2(const char* Ab, const char* Bb, int kb,
                                            char* ldsA, char* ldsB, int tid) {
  {
    const int u = tid + 3 * 512;
    const int row = u >> 3;
    const int sc = ((u & 7) * 16) ^ ((row & 7) << 4);
    gload_lds16(Ab + (size_t)row * 2048 + kb + sc, ldsA + u * 16);
  }
#pragma unroll
  for (int r = 0; r < 2; ++r) {
    const int u = tid + r * 512;
    const int row = u >> 3;
    const int sc = ((u & 7) * 16) ^ ((row & 7) << 4);
    gload_lds16(Bb + (size_t)row * 2048 + kb + sc, ldsB + u * 16);
  }
}

__device__ __forceinline__ void gemm256x128_core(const char* Ab, const char* Bb,
                                                 char* lds,  // 98304 bytes
                                                 f32x4 (&acc)[4][4]) {
  const int tid = threadIdx.x;
  const int lane = tid & 63;
  const int w = tid >> 6;
  const int lr = lane & 15, lg = lane >> 4;
  const int wmb = (w >> 1) * 64;
  const int wnb = (w & 1) * 64;
  char* const A0 = lds;
  char* const A1 = lds + 32768;
  char* const B0 = lds + 65536;
  char* const B1 = lds + 81920;

#pragma unroll
  for (int i = 0; i < 4; i++)
#pragma unroll
    for (int j = 0; j < 4; j++) acc[i][j] = (f32x4){0.f, 0.f, 0.f, 0.f};

  g8_stage_p1(Ab, 0, A0, tid);
  g8_stage_p2(Ab, Bb, 0, A0, B0, tid);
  for (int t = 0; t < 16; ++t) {
    const char* At = (t & 1) ? A1 : A0;
    const char* Bt = (t & 1) ? B1 : B0;
    char* nA = (t & 1) ? A0 : A1;
    char* nB = (t & 1) ? B0 : B1;
    if (t + 1 < 16) {
      g8_stage_p1(Ab, (t + 1) * 128, nA, tid);
      asm volatile("s_waitcnt vmcnt(3)" ::: "memory");
    } else {
      asm volatile("s_waitcnt vmcnt(0)" ::: "memory");
    }
    __builtin_amdgcn_s_barrier();
    __builtin_amdgcn_sched_barrier(0);

    Frag bf0[4], bf1[4];
#pragma unroll
    for (int ni = 0; ni < 4; ni++) {
      const int row = wnb + ni * 16 + lr;
      const int swz = (row & 7) << 4;
      bf0[ni].q = *(const uint4*)(Bt + row * 128 + ((lg * 16) ^ swz));
      bf1[ni].q = *(const uint4*)(Bt + row * 128 + ((64 + lg * 16) ^ swz));
    }
    Frag pa0[2], pa1[2];
#pragma unroll
    for (int mi = 0; mi < 2; mi++) {
      const int row = wmb + mi * 16 + lr;
      const int swz = (row & 7) << 4;
      pa0[mi].q = *(const uint4*)(At + row * 128 + ((lg * 16) ^ swz));
      pa1[mi].q = *(const uint4*)(At + row * 128 + ((64 + lg * 16) ^ swz));
    }
    __builtin_amdgcn_s_setprio(1);
#pragma unroll
    for (int mi = 0; mi < 2; mi++)
#pragma unroll
      for (int ni = 0; ni < 4; ni++) {
        acc[mi][ni] = __builtin_amdgcn_mfma_f32_16x16x32_bf16(pa0[mi].v, bf0[ni].v,
                                                              acc[mi][ni], 0, 0, 0);
        acc[mi][ni] = __builtin_amdgcn_mfma_f32_16x16x32_bf16(pa1[mi].v, bf1[ni].v,
                                                              acc[mi][ni], 0, 0, 0);
      }
    __builtin_amdgcn_s_setprio(0);

    if (t + 1 < 16) g8_stage_p2(Ab, Bb, (t + 1) * 128, nA, nB, tid);
#pragma unroll
    for (int mi = 2; mi < 4; mi++) {
      const int row = wmb + mi * 16 + lr;
      const int swz = (row & 7) << 4;
      Frag qa0, qa1;
      qa0.q = *(const uint4*)(At + row * 128 + ((lg * 16) ^ swz));
      qa1.q = *(const uint4*)(At + row * 128 + ((64 + lg * 16) ^ swz));
      __builtin_amdgcn_s_setprio(1);
#pragma unroll
      for (int ni = 0; ni < 4; ni++) {
        acc[mi][ni] = __builtin_amdgcn_mfma_f32_16x16x32_bf16(qa0.v, bf0[ni].v,
                                                              acc[mi][ni], 0, 0, 0);
        acc[mi][ni] = __builtin_amdgcn_mfma_f32_16x16x32_bf16(qa1.v, bf1[ni].v,
                                                              acc[mi][ni], 0, 0, 0);
      }
      __builtin_amdgcn_s_setprio(0);
    }
    __builtin_amdgcn_s_barrier();
  }
}

// ---------------- V projection GEMM: 256x128, grid 256 = 1 round ----------------

__global__ __launch_bounds__(512, 2) void gemm_v_kernel(const uint16_t* __restrict__ Xb,
    const uint16_t* __restrict__ Wtv, uint16_t* __restrict__ Vt) {
  __shared__ __align__(16) char lds[98304];
  const int m0 = (blockIdx.x & 31) * 256;
  const int n0 = (blockIdx.x >> 5) * 128;
  f32x4 acc[4][4];
  gemm256x128_core((const char*)Xb + (size_t)m0 * 2048, (const char*)Wtv + (size_t)n0 * 2048,
                   lds, acc);

  const int tid = threadIdx.x, w = tid >> 6, lane = tid & 63;
  const int lr = lane & 15, lg = lane >> 4;
  const int wmb = (w >> 1) * 64;

  char* vr = lds + (w & 1) * 33792;  // per-head region [64 d][528B]
#pragma unroll
  for (int mi = 0; mi < 4; mi++)
#pragma unroll
    for (int ni = 0; ni < 4; ni++) {
      const int d = ni * 16 + lr;
      const int tl = wmb + mi * 16 + 4 * lg;
      uint2 pr;
      pr.x = cvtpk(acc[mi][ni][0], acc[mi][ni][1]);
      pr.y = cvtpk(acc[mi][ni][2], acc[mi][ni][3]);
      *(uint2*)(vr + d * 528 + tl * 2) = pr;
    }
  __syncthreads();
  const int bb = m0 >> 11, t0 = m0 & 2047;
  const int h0 = n0 >> 6;
#pragma unroll
  for (int j = 0; j < 8; j++) {
    const int linear = (tid + j * 512) * 16;
    const int rg = linear >> 15;
    const int rem = linear & 32767;
    const int d = rem >> 9;
    const int toff = rem & 511;
    const uint4 val = *(const uint4*)(lds + rg * 33792 + d * 528 + toff);
    const int bh = bb * 16 + h0 + rg;
    *(uint4*)((char*)Vt + ((size_t)(bh * 64 + d) * TSEQ + t0) * 2 + toff) = val;
  }
}

// ---------------- flash attention (swapped-QK^T, 32x32 MFMA) ----------------
// Round-13: uniform work via q-tile PAIRING — each block runs segments
// {15-p, p} sequentially (36 tile-iters for every block; no concurrent-tail).
// Grid 512 = 2 blocks/CU, constant residency to the end.

__device__ __forceinline__ void stage_kv(const char* Kb, const char* Vb, int kv0,
                                         char* kdst, char* vdst, int tid) {
  const int w1024 = (tid >> 6) * 1024;
#pragma unroll
  for (int i = 0; i < 2; i++) {
    const int o = i * 4096 + tid * 16;
    const int row = o >> 7;
    const int scol = (o & 127) ^ ((row & 7) << 4);
    gload_lds16(Kb + (size_t)(kv0 + row) * 128 + scol, kdst + i * 4096 + w1024);
    gload_lds16(Vb + (size_t)row * 4096 + kv0 * 2 + scol, vdst + i * 4096 + w1024);
  }
}

__global__ __launch_bounds__(256, 4) void attn_kernel(const uint16_t* __restrict__ Qw,
    const uint16_t* __restrict__ Kw, const uint16_t* __restrict__ Vtw,
    uint16_t* __restrict__ Ctx) {
  const int bid = blockIdx.x;       // 0..511
  const int p = bid >> 6;           // pair index 0..7
  const int bh = bid & 63;
  const int tid = threadIdx.x;
  const int w = tid >> 6, lane = tid & 63;
  const int lq = lane & 31;
  const int hi = lane >> 5;

  const char* Qb = (const char*)Qw + (size_t)bh * TSEQ * 128;
  const char* Kb = (const char*)Kw + (size_t)bh * TSEQ * 128;
  const char* Vb = (const char*)Vtw + (size_t)bh * 64 * 4096;
  const int bb = bh >> 4, hh = bh & 15;

  __shared__ __align__(16) char kbuf[2][8192];
  __shared__ __align__(16) char vbuf[2][8192];

#pragma unroll
  for (int seg = 0; seg < 2; ++seg) {
    const int qt = seg ? p : (15 - p);
    const int wq0 = qt * 128 + w * 32;

    Frag qa[4];
#pragma unroll
    for (int kc = 0; kc < 4; kc++)
      qa[kc].q = *(const uint4*)(Qb + (size_t)(wq0 + lq) * 128 + kc * 32 + hi * 16);

    f32x16 o0 = 0.f, o1 = 0.f;
    // mrun=0 valid init under defer-max invariant (mt-mrun<=8 => P<=2^8);
    // avoids the guaranteed first-tile rescale of -inf init.
    float mrun = 0.f, lrun = 0.f;

    const int nt = 2 * qt + 2;
    stage_kv(Kb, Vb, 0, kbuf[0], vbuf[0], tid);
    int cur = 0;
    for (int t = 0; t < nt; ++t) {
      const int kv0 = t * 64;
      if (t + 1 < nt) {
        stage_kv(Kb, Vb, kv0 + 64, kbuf[cur ^ 1], vbuf[cur ^ 1], tid);
        asm volatile("s_waitcnt vmcnt(4)" ::: "memory");
      } else {
        asm volatile("s_waitcnt vmcnt(0)" ::: "memory");
      }
      __builtin_amdgcn_s_barrier();
      __builtin_amdgcn_sched_barrier(0);

      if (kv0 <= wq0 + 31) {
        const char* Kt = kbuf[cur];
        const char* Vt = vbuf[cur];
        // ---- S^T = K Q^T ----
        f32x16 s[2];
#pragma unroll
        for (int kvh = 0; kvh < 2; kvh++) {
          f32x16 acc = 0.f;
#pragma unroll
          for (int kc = 0; kc < 4; kc++) {
            const int row = kvh * 32 + lq;
            Frag kf;
            kf.q = *(const uint4*)(Kt + row * 128 + ((kc * 32 + hi * 16) ^ ((row & 7) << 4)));
            acc = __builtin_amdgcn_mfma_f32_32x32x16_bf16(kf.v, qa[kc].v, acc, 0, 0, 0);
          }
          s[kvh] = acc;
        }
        // ---- causal mask (diagonal tiles only) ----
        if (kv0 + 63 > wq0) {
          const int q_abs = wq0 + lq;
#pragma unroll
          for (int kvh = 0; kvh < 2; kvh++)
#pragma unroll
            for (int r = 0; r < 16; r++) {
              const int kv_abs = kv0 + kvh * 32 + (r & 3) + 8 * (r >> 2) + 4 * hi;
              if (kv_abs > q_abs) s[kvh][r] = -1e30f;
            }
        }
        // ---- tile max: pairwise tree ----
        float t8[8];
#pragma unroll
        for (int i = 0; i < 8; i++)
          t8[i] = fmaxf(fmaxf(s[0][2 * i], s[0][2 * i + 1]),
                        fmaxf(s[1][2 * i], s[1][2 * i + 1]));
        float t4a = fmaxf(t8[0], t8[1]), t4b = fmaxf(t8[2], t8[3]);
        float t4c = fmaxf(t8[4], t8[5]), t4d = fmaxf(t8[6], t8[7]);
        float mt = fmaxf(fmaxf(t4a, t4b), fmaxf(t4c, t4d));
        mt = fmaxf(mt, __shfl_xor(mt, 32));
        // ---- defer-max (T13) ----
        if (!__all(mt - mrun <= 8.0f)) {
          const float mnew = fmaxf(mrun, mt);
          const float corr = fexp2(mrun - mnew);
          mrun = mnew;
          lrun *= corr;
          o0 *= corr;
          o1 *= corr;
        }
        // ---- P = exp2(S - mrun) ----
#pragma unroll
        for (int kvh = 0; kvh < 2; kvh++)
#pragma unroll
          for (int r = 0; r < 16; r++) s[kvh][r] = fexp2(s[kvh][r] - mrun);
        float ps = 0.f;
#pragma unroll
        for (int kvh = 0; kvh < 2; kvh++)
#pragma unroll
          for (int r = 0; r < 16; r++) ps += s[kvh][r];
        ps += __shfl_xor(ps, 32);
        lrun += ps;
        // ---- pack P to bf16 pairs (hw cvt_pk) ----
        uint32_t pk[2][8];
#pragma unroll
        for (int kvh = 0; kvh < 2; kvh++)
#pragma unroll
          for (int j = 0; j < 8; j++)
            pk[kvh][j] = cvtpk(s[kvh][2 * j], s[kvh][2 * j + 1]);
        // ---- O^T += V^T P^T (permlane32_swap exchange) ----
#pragma unroll
        for (int c16 = 0; c16 < 4; c16++) {
          const int kvh = c16 >> 1, cl = c16 & 1;
          uint32_t x0 = pk[kvh][4 * cl + 0], y0 = pk[kvh][4 * cl + 2];
          uint32_t x1 = pk[kvh][4 * cl + 1], y1 = pk[kvh][4 * cl + 3];
          plane32swap(x0, y0);
          plane32swap(x1, y1);
          Frag pb;
          pb.q.x = x0;
          pb.q.y = x1;
          pb.q.z = y0;
          pb.q.w = y1;
#pragma unroll
          for (int dblk = 0; dblk < 2; dblk++) {
            const int row = dblk * 32 + lq;
            Frag vf;
            vf.q = *(const uint4*)(Vt + row * 128 + ((c16 * 32 + hi * 16) ^ ((row & 7) << 4)));
            if (dblk == 0)
              o0 = __builtin_amdgcn_mfma_f32_32x32x16_bf16(vf.v, pb.v, o0, 0, 0, 0);
            else
              o1 = __builtin_amdgcn_mfma_f32_32x32x16_bf16(vf.v, pb.v, o1, 0, 0, 0);
          }
        }
      }
      __builtin_amdgcn_s_barrier();
      cur ^= 1;
    }

    // ---- segment epilogue ----
    const float inv = 1.0f / lrun;
    const int q_abs = wq0 + lq;
    uint16_t* crow = Ctx + ((size_t)bb * TSEQ + q_abs) * DMODEL + hh * 64;
#pragma unroll
    for (int dblk = 0; dblk < 2; dblk++)
#pragma unroll
      for (int g2 = 0; g2 < 4; g2++) {
        const float a0 = (dblk ? o1[4 * g2 + 0] : o0[4 * g2 + 0]) * inv;
        const float a1 = (dblk ? o1[4 * g2 + 1] : o0[4 * g2 + 1]) * inv;
        const float a2 = (dblk ? o1[4 * g2 + 2] : o0[4 * g2 + 2]) * inv;
        const float a3 = (dblk ? o1[4 * g2 + 3] : o0[4 * g2 + 3]) * inv;
        uint2 st;
        st.x = cvtpk(a0, a1);
        st.y = cvtpk(a2, a3);
        *(uint2*)(crow + dblk * 32 + 8 * g2 + 4 * hi) = st;
      }
  }
}

// ---------------- output projection + bias ----------------

__global__ __launch_bounds__(512, 2) void gemm_out_kernel(const uint16_t* __restrict__ Cb,
    const uint16_t* __restrict__ Wot, const float* __restrict__ bo,
    float* __restrict__ out) {
  __shared__ __align__(16) char lds[98304];
  const int m0 = (blockIdx.x & 31) * 256;
  const int n0 = (blockIdx.x >> 5) * 128;
  f32x4 acc[4][4];
  gemm256x128_core((const char*)Cb + (size_t)m0 * 2048, (const char*)Wot + (size_t)n0 * 2048,
                   lds, acc);

  const int tid = threadIdx.x, w = tid >> 6, lane = tid & 63;
  const int lr = lane & 15, lg = lane >> 4;
  const int wmb = (w >> 1) * 64, wnb = (w & 1) * 64;
#pragma unroll
  for (int mi = 0; mi < 4; mi++)
#pragma unroll
    for (int ni = 0; ni < 4; ni++) {
      const int col = n0 + wnb + ni * 16 + lr;
      const float bias = bo[col];
#pragma unroll
      for (int r = 0; r < 4; r++) {
        const int row = m0 + wmb + mi * 16 + 4 * lg + r;
        out[(size_t)row * DMODEL + col] = acc[mi][ni][r] + bias;
      }
    }
}

// ---------------- launch ----------------

extern "C" void kernel_launch(void* const* d_in, const int* in_sizes, int n_in,
                              void* d_out, int out_size, void* d_ws, size_t ws_size,
                              hipStream_t stream) {
  const float* x  = (const float*)d_in[0];
  const float* Wq = (const float*)d_in[1];
  const float* Wk = (const float*)d_in[2];
  const float* Wv = (const float*)d_in[3];
  const float* Wo = (const float*)d_in[4];
  const float* bo = (const float*)d_in[5];
  float* out = (float*)d_out;

  char* ws = (char*)d_ws;
  uint16_t* Xb    = (uint16_t*)(ws);                      // 16 MiB [8192][1024]
  uint16_t* Ctx   = (uint16_t*)(ws);                      // aliases Xb (dead after QKV GEMMs)
  uint16_t* Wqkvt = (uint16_t*)(ws + (16u << 20));        //  6 MiB [3072][1024] (W^T)
  uint16_t* Wot   = (uint16_t*)(ws + (22u << 20));        //  2 MiB [1024][1024] (Wo^T)
  uint16_t* Qw    = (uint16_t*)(ws + (24u << 20));        // 16 MiB [64][2048][64]
  uint16_t* Kw    = (uint16_t*)(ws + (40u << 20));        // 16 MiB [64][2048][64]
  uint16_t* Vtw   = (uint16_t*)(ws + (56u << 20));        // 16 MiB [64][64][2048]
  (void)ws_size; (void)in_sizes; (void)n_in; (void)out_size;

  cvt_x_kernel<<<8192, 256, 0, stream>>>(x, Xb, 2097152);
  cvt_w_kernel<<<dim3(32, 32, 4), dim3(32, 8), 0, stream>>>(Wq, Wk, Wv, Wo, Wqkvt, Wot);
  gemm_qk_kernel<<<256, 512, 0, stream>>>(Xb, Wqkvt, Qw, Kw);
  gemm_v_kernel<<<256, 512, 0, stream>>>(Xb, Wqkvt + (size_t)2048 * 1024, Vtw);
  attn_kernel<<<512, 256, 0, stream>>>(Qw, Kw, Vtw, Ctx);
  gemm_out_kernel<<<256, 512, 0, stream>>>(Ctx, Wot, bo, out);
}

// Round 15
// 157.396 us; speedup vs baseline: 1.0816x; 1.0816x over previous
//
#include <hip/hip_runtime.h>
#include <hip/hip_bf16.h>
#include <stdint.h>

#define TSEQ 2048
#define DMODEL 1024

typedef __attribute__((ext_vector_type(8))) short bf16x8;
typedef __attribute__((ext_vector_type(4))) float f32x4;
typedef __attribute__((ext_vector_type(16))) float f32x16;
typedef __attribute__((ext_vector_type(2))) int int2v;

union Frag { bf16x8 v; uint4 q; };

__device__ __forceinline__ uint16_t f2bfu(float f) {
  uint32_t u = __builtin_bit_cast(uint32_t, f);
  u += 0x7fffu + ((u >> 16) & 1u);
  return (uint16_t)(u >> 16);
}

__device__ __forceinline__ uint32_t pk2bf(float a, float b) {
  return ((uint32_t)f2bfu(b) << 16) | f2bfu(a);
}

// hardware packed f32->bf16 (RTNE), low half = first operand
__device__ __forceinline__ uint32_t cvtpk(float a, float b) {
  uint32_t r;
  asm("v_cvt_pk_bf16_f32 %0, %1, %2" : "=v"(r) : "v"(a), "v"(b));
  return r;
}

// Swap halves between two regs: on return a = {a.lo31, b.lo31}, b = {a.hi31, b.hi31}
__device__ __forceinline__ void plane32swap(uint32_t& a, uint32_t& b) {
#if __has_builtin(__builtin_amdgcn_permlane32_swap)
  int2v r = __builtin_amdgcn_permlane32_swap((int)a, (int)b, false, false);
  a = (uint32_t)r[0];
  b = (uint32_t)r[1];
#else
  const uint32_t sa = (uint32_t)__shfl_xor((int)a, 32);
  const uint32_t sb = (uint32_t)__shfl_xor((int)b, 32);
  const bool hi = (threadIdx.x & 63) >= 32;
  const uint32_t na = hi ? sb : a;
  const uint32_t nb = hi ? b : sa;
  a = na;
  b = nb;
#endif
}

__device__ __forceinline__ float fexp2(float x) {
#if __has_builtin(__builtin_amdgcn_exp2f)
  return __builtin_amdgcn_exp2f(x);
#else
  return exp2f(x);
#endif
}

__device__ __forceinline__ void gload_lds16(const void* g, void* l) {
  __builtin_amdgcn_global_load_lds(
      (const __attribute__((address_space(1))) void*)g,
      (__attribute__((address_space(3))) void*)l, 16, 0, 0);
}

// ---------------- prep kernels ----------------

__global__ __launch_bounds__(256) void cvt_x_kernel(const float* __restrict__ x,
                                                    uint16_t* __restrict__ xb, int n4) {
  int i = blockIdx.x * 256 + threadIdx.x;
  if (i >= n4) return;
  float4 v = ((const float4*)x)[i];
  ushort4 o;
  o.x = f2bfu(v.x); o.y = f2bfu(v.y); o.z = f2bfu(v.z); o.w = f2bfu(v.w);
  ((ushort4*)xb)[i] = o;
}

// dst[n][k] = src[k][n], fp32 -> bf16.  Wq gets 0.125*log2(e) folded in (exp2 softmax).
__global__ __launch_bounds__(256) void cvt_w_kernel(const float* __restrict__ Wq,
    const float* __restrict__ Wk, const float* __restrict__ Wv, const float* __restrict__ Wo,
    uint16_t* __restrict__ Wqkvt, uint16_t* __restrict__ Wot) {
  const float* src = (blockIdx.z == 0) ? Wq : (blockIdx.z == 1) ? Wk
                   : (blockIdx.z == 2) ? Wv : Wo;
  uint16_t* dst = (blockIdx.z < 3) ? (Wqkvt + (size_t)blockIdx.z * DMODEL * DMODEL) : Wot;
  const float wscale = (blockIdx.z == 0) ? 0.125f * 1.4426950408889634f : 1.0f;
  __shared__ float tile[32][33];
  const int x0 = blockIdx.x * 32, y0 = blockIdx.y * 32;
  for (int ii = 0; ii < 4; ii++) {
    int i = threadIdx.y + ii * 8;
    tile[i][threadIdx.x] = src[(size_t)(y0 + i) * DMODEL + x0 + threadIdx.x];
  }
  __syncthreads();
  for (int ii = 0; ii < 4; ii++) {
    int i = threadIdx.y + ii * 8;
    dst[(size_t)(x0 + i) * DMODEL + y0 + threadIdx.x] = f2bfu(tile[threadIdx.x][i] * wscale);
  }
}

// ---- shared staging helper: 256 rows x 64 K (32KB), 4 x 512 threads ----
__device__ __forceinline__ void stage256(const char* Gb, int kb, char* ldsT, int tid) {
#pragma unroll
  for (int r = 0; r < 4; ++r) {
    const int u = tid + r * 512;
    const int row = u >> 3;
    const int sc = ((u & 7) * 16) ^ ((row & 7) << 4);
    gload_lds16(Gb + (size_t)row * 2048 + kb + sc, ldsT + u * 16);
  }
}

// ======== 256x256 GEMM core: per-wave 128x64 (m201 geometry) ========

__device__ __forceinline__ void gemm256sq_core(const char* Ab, const char* Bb,
                                               char* lds,  // 131072 bytes
                                               f32x4 (&acc)[8][4]) {
  const int tid = threadIdx.x;
  const int lane = tid & 63;
  const int w = tid >> 6;
  const int lr = lane & 15, lg = lane >> 4;
  const int wmb = (w >> 2) * 128;  // 0,128
  const int wnb = (w & 3) * 64;    // 0,64,128,192
  char* const A0 = lds;
  char* const A1 = lds + 32768;
  char* const B0 = lds + 65536;
  char* const B1 = lds + 98304;

#pragma unroll
  for (int i = 0; i < 8; i++)
#pragma unroll
    for (int j = 0; j < 4; j++) acc[i][j] = (f32x4){0.f, 0.f, 0.f, 0.f};

  stage256(Ab, 0, A0, tid);
  stage256(Bb, 0, B0, tid);
  for (int t = 0; t < 16; ++t) {
    const char* At = (t & 1) ? A1 : A0;
    const char* Bt = (t & 1) ? B1 : B0;
    char* nA = (t & 1) ? A0 : A1;
    char* nB = (t & 1) ? B0 : B1;
    if (t + 1 < 16) {
      stage256(Ab, (t + 1) * 128, nA, tid);                // A(t+1) in flight
      asm volatile("s_waitcnt vmcnt(4)" ::: "memory");     // tile t fully landed
    } else {
      asm volatile("s_waitcnt vmcnt(0)" ::: "memory");
    }
    __builtin_amdgcn_s_barrier();                          // buffer t ready
    __builtin_amdgcn_sched_barrier(0);

    Frag bf0[4], bf1[4];
#pragma unroll
    for (int ni = 0; ni < 4; ni++) {
      const int row = wnb + ni * 16 + lr;
      const int swz = (row & 7) << 4;
      bf0[ni].q = *(const uint4*)(Bt + row * 128 + ((lg * 16) ^ swz));
      bf1[ni].q = *(const uint4*)(Bt + row * 128 + ((64 + lg * 16) ^ swz));
    }
#pragma unroll
    for (int ph = 0; ph < 4; ph++) {
      Frag a0[2], a1[2];
#pragma unroll
      for (int i = 0; i < 2; i++) {
        const int row = wmb + (2 * ph + i) * 16 + lr;
        const int swz = (row & 7) << 4;
        a0[i].q = *(const uint4*)(At + row * 128 + ((lg * 16) ^ swz));
        a1[i].q = *(const uint4*)(At + row * 128 + ((64 + lg * 16) ^ swz));
      }
      __builtin_amdgcn_s_setprio(1);
#pragma unroll
      for (int i = 0; i < 2; i++) {
        const int mi = 2 * ph + i;
#pragma unroll
        for (int ni = 0; ni < 4; ni++) {
          acc[mi][ni] = __builtin_amdgcn_mfma_f32_16x16x32_bf16(a0[i].v, bf0[ni].v,
                                                                acc[mi][ni], 0, 0, 0);
          acc[mi][ni] = __builtin_amdgcn_mfma_f32_16x16x32_bf16(a1[i].v, bf1[ni].v,
                                                                acc[mi][ni], 0, 0, 0);
        }
      }
      __builtin_amdgcn_s_setprio(0);
      if (ph == 0 && t + 1 < 16) stage256(Bb, (t + 1) * 128, nB, tid);  // B(t+1)
    }
    __builtin_amdgcn_s_barrier();                          // buffer t consumed
  }
}

// ======== 256x128 GEMM core (round-9 verified) ========

__device__ __forceinline__ void g8_stage_p1(const char* Ab, int kb, char* ldsA, int tid) {
#pragma unroll
  for (int r = 0; r < 3; ++r) {
    const int u = tid + r * 512;
    const int row = u >> 3;
    const int sc = ((u & 7) * 16) ^ ((row & 7) << 4);
    gload_lds16(Ab + (size_t)row * 2048 + kb + sc, ldsA + u * 16);
  }
}

__device__ __forceinline__ void g8_stage_p2(const char* Ab, const char* Bb, int kb,
                                            char* ldsA, char* ldsB, int tid) {
  {
    const int u = tid + 3 * 512;
    const int row = u >> 3;
    const int sc = ((u & 7) * 16) ^ ((row & 7) << 4);
    gload_lds16(Ab + (size_t)row * 2048 + kb + sc, ldsA + u * 16);
  }
#pragma unroll
  for (int r = 0; r < 2; ++r) {
    const int u = tid + r * 512;
    const int row = u >> 3;
    const int sc = ((u & 7) * 16) ^ ((row & 7) << 4);
    gload_lds16(Bb + (size_t)row * 2048 + kb + sc, ldsB + u * 16);
  }
}

__device__ __forceinline__ void gemm256x128_core(const char* Ab, const char* Bb,
                                                 char* lds,  // 98304 bytes
                                                 f32x4 (&acc)[4][4]) {
  const int tid = threadIdx.x;
  const int lane = tid & 63;
  const int w = tid >> 6;
  const int lr = lane & 15, lg = lane >> 4;
  const int wmb = (w >> 1) * 64;
  const int wnb = (w & 1) * 64;
  char* const A0 = lds;
  char* const A1 = lds + 32768;
  char* const B0 = lds + 65536;
  char* const B1 = lds + 81920;

#pragma unroll
  for (int i = 0; i < 4; i++)
#pragma unroll
    for (int j = 0; j < 4; j++) acc[i][j] = (f32x4){0.f, 0.f, 0.f, 0.f};

  g8_stage_p1(Ab, 0, A0, tid);
  g8_stage_p2(Ab, Bb, 0, A0, B0, tid);
  for (int t = 0; t < 16; ++t) {
    const char* At = (t & 1) ? A1 : A0;
    const char* Bt = (t & 1) ? B1 : B0;
    char* nA = (t & 1) ? A0 : A1;
    char* nB = (t & 1) ? B0 : B1;
    if (t + 1 < 16) {
      g8_stage_p1(Ab, (t + 1) * 128, nA, tid);
      asm volatile("s_waitcnt vmcnt(3)" ::: "memory");
    } else {
      asm volatile("s_waitcnt vmcnt(0)" ::: "memory");
    }
    __builtin_amdgcn_s_barrier();
    __builtin_amdgcn_sched_barrier(0);

    Frag bf0[4], bf1[4];
#pragma unroll
    for (int ni = 0; ni < 4; ni++) {
      const int row = wnb + ni * 16 + lr;
      const int swz = (row & 7) << 4;
      bf0[ni].q = *(const uint4*)(Bt + row * 128 + ((lg * 16) ^ swz));
      bf1[ni].q = *(const uint4*)(Bt + row * 128 + ((64 + lg * 16) ^ swz));
    }
    Frag pa0[2], pa1[2];
#pragma unroll
    for (int mi = 0; mi < 2; mi++) {
      const int row = wmb + mi * 16 + lr;
      const int swz = (row & 7) << 4;
      pa0[mi].q = *(const uint4*)(At + row * 128 + ((lg * 16) ^ swz));
      pa1[mi].q = *(const uint4*)(At + row * 128 + ((64 + lg * 16) ^ swz));
    }
    __builtin_amdgcn_s_setprio(1);
#pragma unroll
    for (int mi = 0; mi < 2; mi++)
#pragma unroll
      for (int ni = 0; ni < 4; ni++) {
        acc[mi][ni] = __builtin_amdgcn_mfma_f32_16x16x32_bf16(pa0[mi].v, bf0[ni].v,
                                                              acc[mi][ni], 0, 0, 0);
        acc[mi][ni] = __builtin_amdgcn_mfma_f32_16x16x32_bf16(pa1[mi].v, bf1[ni].v,
                                                              acc[mi][ni], 0, 0, 0);
      }
    __builtin_amdgcn_s_setprio(0);

    if (t + 1 < 16) g8_stage_p2(Ab, Bb, (t + 1) * 128, nA, nB, tid);
#pragma unroll
    for (int mi = 2; mi < 4; mi++) {
      const int row = wmb + mi * 16 + lr;
      const int swz = (row & 7) << 4;
      Frag qa0, qa1;
      qa0.q = *(const uint4*)(At + row * 128 + ((lg * 16) ^ swz));
      qa1.q = *(const uint4*)(At + row * 128 + ((64 + lg * 16) ^ swz));
      __builtin_amdgcn_s_setprio(1);
#pragma unroll
      for (int ni = 0; ni < 4; ni++) {
        acc[mi][ni] = __builtin_amdgcn_mfma_f32_16x16x32_bf16(qa0.v, bf0[ni].v,
                                                              acc[mi][ni], 0, 0, 0);
        acc[mi][ni] = __builtin_amdgcn_mfma_f32_16x16x32_bf16(qa1.v, bf1[ni].v,
                                                              acc[mi][ni], 0, 0, 0);
      }
      __builtin_amdgcn_s_setprio(0);
    }
    __builtin_amdgcn_s_barrier();
  }
}

// ---------------- fused QKV projection: 512 blocks = QK round + V round ----------
// blocks 0..255: 256x256 QK tiles (dispatched first); 256..511: 256x128 V tiles.
// V blocks backfill CUs as QK blocks finish (removes inter-kernel barrier).

__global__ __launch_bounds__(512, 2) void gemm_qkv_fused(const uint16_t* __restrict__ Xb,
    const uint16_t* __restrict__ Wt, uint16_t* __restrict__ Qo,
    uint16_t* __restrict__ Ko, uint16_t* __restrict__ Vt) {
  __shared__ __align__(16) char lds[131072];
  const int tid = threadIdx.x, w = tid >> 6, lane = tid & 63;
  const int lr = lane & 15, lg = lane >> 4;

  if (blockIdx.x < 256) {
    // ---- QK path ----
    const int m0 = (blockIdx.x & 31) * 256;
    const int n0 = (blockIdx.x >> 5) * 256;
    f32x4 acc[8][4];
    gemm256sq_core((const char*)Xb + (size_t)m0 * 2048, (const char*)Wt + (size_t)n0 * 2048,
                   lds, acc);
    const int wmb = (w >> 2) * 128, wnb = (w & 3) * 64;
#pragma unroll
    for (int mi = 0; mi < 8; mi++)
#pragma unroll
      for (int ni = 0; ni < 4; ni++) {
        const int col = n0 + wnb + ni * 16 + lr;
        const int p = col >> 10, c = col & 1023, h = c >> 6, d = c & 63;
#pragma unroll
        for (int r = 0; r < 4; r++) {
          const int row = m0 + wmb + mi * 16 + 4 * lg + r;
          const int bb = row >> 11, t = row & 2047;
          const int bh = bb * 16 + h;
          const uint16_t val = f2bfu(acc[mi][ni][r]);
          if (p == 0) Qo[((size_t)bh * TSEQ + t) * 64 + d] = val;
          else        Ko[((size_t)bh * TSEQ + t) * 64 + d] = val;
        }
      }
  } else {
    // ---- V path ----
    const int vb = blockIdx.x - 256;
    const int m0 = (vb & 31) * 256;
    const int n0 = (vb >> 5) * 128;
    const uint16_t* Wtv = Wt + (size_t)2048 * 1024;
    f32x4 acc[4][4];
    gemm256x128_core((const char*)Xb + (size_t)m0 * 2048, (const char*)Wtv + (size_t)n0 * 2048,
                     lds, acc);
    const int wmb = (w >> 1) * 64;
    char* vr = lds + (w & 1) * 33792;  // per-head region [64 d][528B]
#pragma unroll
    for (int mi = 0; mi < 4; mi++)
#pragma unroll
      for (int ni = 0; ni < 4; ni++) {
        const int d = ni * 16 + lr;
        const int tl = wmb + mi * 16 + 4 * lg;
        uint2 pr;
        pr.x = cvtpk(acc[mi][ni][0], acc[mi][ni][1]);
        pr.y = cvtpk(acc[mi][ni][2], acc[mi][ni][3]);
        *(uint2*)(vr + d * 528 + tl * 2) = pr;
      }
    __syncthreads();
    const int bb = m0 >> 11, t0 = m0 & 2047;
    const int h0 = n0 >> 6;
#pragma unroll
    for (int j = 0; j < 8; j++) {
      const int linear = (tid + j * 512) * 16;
      const int rg = linear >> 15;
      const int rem = linear & 32767;
      const int d = rem >> 9;
      const int toff = rem & 511;
      const uint4 val = *(const uint4*)(lds + rg * 33792 + d * 528 + toff);
      const int bh = bb * 16 + h0 + rg;
      *(uint4*)((char*)Vt + ((size_t)(bh * 64 + d) * TSEQ + t0) * 2 + toff) = val;
    }
  }
}

// ---------------- flash attention (round-12 exact: best measured 58.4 us) -------
// grid 1024 = 4 blocks/CU, balanced heavy-first mapping; permlane32_swap
// P-exchange; defer-max THR=8; hw cvt_pk.  Residency (16 waves/CU) is the
// lever — pairing into 512 blocks (8 waves/CU) regressed 18% (round 13).

__device__ __forceinline__ void stage_kv(const char* Kb, const char* Vb, int kv0,
                                         char* kdst, char* vdst, int tid) {
  const int w1024 = (tid >> 6) * 1024;
#pragma unroll
  for (int i = 0; i < 2; i++) {
    const int o = i * 4096 + tid * 16;
    const int row = o >> 7;
    const int scol = (o & 127) ^ ((row & 7) << 4);
    gload_lds16(Kb + (size_t)(kv0 + row) * 128 + scol, kdst + i * 4096 + w1024);
    gload_lds16(Vb + (size_t)row * 4096 + kv0 * 2 + scol, vdst + i * 4096 + w1024);
  }
}

__global__ __launch_bounds__(256, 4) void attn_kernel(const uint16_t* __restrict__ Qw,
    const uint16_t* __restrict__ Kw, const uint16_t* __restrict__ Vtw,
    uint16_t* __restrict__ Ctx) {
  const int bid = blockIdx.x;
  // balanced mapping: CU slot c gets rounds with qt {15-g, 8+g, 7-g, g} (sum 30)
  const int c = bid & 255;
  const int rd = bid >> 8;
  const int g = c >> 6;
  int qt;
  if (rd == 0)      qt = 15 - g;
  else if (rd == 1) qt = 8 + g;
  else if (rd == 2) qt = 7 - g;
  else              qt = g;
  const int bh = c & 63;
  const int tid = threadIdx.x;
  const int w = tid >> 6, lane = tid & 63;
  const int lq = lane & 31;
  const int hi = lane >> 5;
  const int wq0 = qt * 128 + w * 32;

  const char* Qb = (const char*)Qw + (size_t)bh * TSEQ * 128;
  const char* Kb = (const char*)Kw + (size_t)bh * TSEQ * 128;
  const char* Vb = (const char*)Vtw + (size_t)bh * 64 * 4096;

  __shared__ __align__(16) char kbuf[2][8192];
  __shared__ __align__(16) char vbuf[2][8192];

  Frag qa[4];
#pragma unroll
  for (int kc = 0; kc < 4; kc++)
    qa[kc].q = *(const uint4*)(Qb + (size_t)(wq0 + lq) * 128 + kc * 32 + hi * 16);

  f32x16 o0 = 0.f, o1 = 0.f;
  float mrun = -1e30f, lrun = 0.f;

  const int nt = 2 * qt + 2;
  stage_kv(Kb, Vb, 0, kbuf[0], vbuf[0], tid);
  int cur = 0;
  for (int t = 0; t < nt; ++t) {
    const int kv0 = t * 64;
    if (t + 1 < nt) {
      stage_kv(Kb, Vb, kv0 + 64, kbuf[cur ^ 1], vbuf[cur ^ 1], tid);
      asm volatile("s_waitcnt vmcnt(4)" ::: "memory");
    } else {
      asm volatile("s_waitcnt vmcnt(0)" ::: "memory");
    }
    __builtin_amdgcn_s_barrier();
    __builtin_amdgcn_sched_barrier(0);

    if (kv0 <= wq0 + 31) {
      const char* Kt = kbuf[cur];
      const char* Vt = vbuf[cur];
      // ---- S^T = K Q^T ----
      f32x16 s[2];
#pragma unroll
      for (int kvh = 0; kvh < 2; kvh++) {
        f32x16 acc = 0.f;
#pragma unroll
        for (int kc = 0; kc < 4; kc++) {
          const int row = kvh * 32 + lq;
          Frag kf;
          kf.q = *(const uint4*)(Kt + row * 128 + ((kc * 32 + hi * 16) ^ ((row & 7) << 4)));
          acc = __builtin_amdgcn_mfma_f32_32x32x16_bf16(kf.v, qa[kc].v, acc, 0, 0, 0);
        }
        s[kvh] = acc;
      }
      // ---- causal mask (diagonal tiles only) ----
      if (kv0 + 63 > wq0) {
        const int q_abs = wq0 + lq;
#pragma unroll
        for (int kvh = 0; kvh < 2; kvh++)
#pragma unroll
          for (int r = 0; r < 16; r++) {
            const int kv_abs = kv0 + kvh * 32 + (r & 3) + 8 * (r >> 2) + 4 * hi;
            if (kv_abs > q_abs) s[kvh][r] = -1e30f;
          }
      }
      // ---- tile max: pairwise tree ----
      float t8[8];
#pragma unroll
      for (int i = 0; i < 8; i++)
        t8[i] = fmaxf(fmaxf(s[0][2 * i], s[0][2 * i + 1]),
                      fmaxf(s[1][2 * i], s[1][2 * i + 1]));
      float t4a = fmaxf(t8[0], t8[1]), t4b = fmaxf(t8[2], t8[3]);
      float t4c = fmaxf(t8[4], t8[5]), t4d = fmaxf(t8[6], t8[7]);
      float mt = fmaxf(fmaxf(t4a, t4b), fmaxf(t4c, t4d));
      mt = fmaxf(mt, __shfl_xor(mt, 32));
      // ---- defer-max (T13) ----
      if (!__all(mt - mrun <= 8.0f)) {
        const float mnew = fmaxf(mrun, mt);
        const float corr = fexp2(mrun - mnew);
        mrun = mnew;
        lrun *= corr;
        o0 *= corr;
        o1 *= corr;
      }
      // ---- P = exp2(S - mrun) ----
#pragma unroll
      for (int kvh = 0; kvh < 2; kvh++)
#pragma unroll
        for (int r = 0; r < 16; r++) s[kvh][r] = fexp2(s[kvh][r] - mrun);
      float ps = 0.f;
#pragma unroll
      for (int kvh = 0; kvh < 2; kvh++)
#pragma unroll
        for (int r = 0; r < 16; r++) ps += s[kvh][r];
      ps += __shfl_xor(ps, 32);
      lrun += ps;
      // ---- pack P to bf16 pairs (hw cvt_pk) ----
      uint32_t pk[2][8];
#pragma unroll
      for (int kvh = 0; kvh < 2; kvh++)
#pragma unroll
        for (int j = 0; j < 8; j++)
          pk[kvh][j] = cvtpk(s[kvh][2 * j], s[kvh][2 * j + 1]);
      // ---- O^T += V^T P^T (permlane32_swap exchange) ----
#pragma unroll
      for (int c16 = 0; c16 < 4; c16++) {
        const int kvh = c16 >> 1, cl = c16 & 1;
        uint32_t x0 = pk[kvh][4 * cl + 0], y0 = pk[kvh][4 * cl + 2];
        uint32_t x1 = pk[kvh][4 * cl + 1], y1 = pk[kvh][4 * cl + 3];
        plane32swap(x0, y0);   // x0 = {lo,lo} -> k{0,1}; y0 = {hi,hi} -> k{4,5}
        plane32swap(x1, y1);
        Frag pb;
        pb.q.x = x0;
        pb.q.y = x1;
        pb.q.z = y0;
        pb.q.w = y1;
#pragma unroll
        for (int dblk = 0; dblk < 2; dblk++) {
          const int row = dblk * 32 + lq;
          Frag vf;
          vf.q = *(const uint4*)(Vt + row * 128 + ((c16 * 32 + hi * 16) ^ ((row & 7) << 4)));
          if (dblk == 0)
            o0 = __builtin_amdgcn_mfma_f32_32x32x16_bf16(vf.v, pb.v, o0, 0, 0, 0);
          else
            o1 = __builtin_amdgcn_mfma_f32_32x32x16_bf16(vf.v, pb.v, o1, 0, 0, 0);
        }
      }
    }
    __builtin_amdgcn_s_barrier();
    cur ^= 1;
  }

  const int bb = bh >> 4, hh = bh & 15;
  const float inv = 1.0f / lrun;
  const int q_abs = wq0 + lq;
  uint16_t* crow = Ctx + ((size_t)bb * TSEQ + q_abs) * DMODEL + hh * 64;
#pragma unroll
  for (int dblk = 0; dblk < 2; dblk++)
#pragma unroll
    for (int g2 = 0; g2 < 4; g2++) {
      const float a0 = (dblk ? o1[4 * g2 + 0] : o0[4 * g2 + 0]) * inv;
      const float a1 = (dblk ? o1[4 * g2 + 1] : o0[4 * g2 + 1]) * inv;
      const float a2 = (dblk ? o1[4 * g2 + 2] : o0[4 * g2 + 2]) * inv;
      const float a3 = (dblk ? o1[4 * g2 + 3] : o0[4 * g2 + 3]) * inv;
      uint2 st;
      st.x = cvtpk(a0, a1);
      st.y = cvtpk(a2, a3);
      *(uint2*)(crow + dblk * 32 + 8 * g2 + 4 * hi) = st;
    }
}

// ---------------- output projection + bias ----------------

__global__ __launch_bounds__(512, 2) void gemm_out_kernel(const uint16_t* __restrict__ Cb,
    const uint16_t* __restrict__ Wot, const float* __restrict__ bo,
    float* __restrict__ out) {
  __shared__ __align__(16) char lds[98304];
  const int m0 = (blockIdx.x & 31) * 256;
  const int n0 = (blockIdx.x >> 5) * 128;
  f32x4 acc[4][4];
  gemm256x128_core((const char*)Cb + (size_t)m0 * 2048, (const char*)Wot + (size_t)n0 * 2048,
                   lds, acc);

  const int tid = threadIdx.x, w = tid >> 6, lane = tid & 63;
  const int lr = lane & 15, lg = lane >> 4;
  const int wmb = (w >> 1) * 64, wnb = (w & 1) * 64;
#pragma unroll
  for (int mi = 0; mi < 4; mi++)
#pragma unroll
    for (int ni = 0; ni < 4; ni++) {
      const int col = n0 + wnb + ni * 16 + lr;
      const float bias = bo[col];
#pragma unroll
      for (int r = 0; r < 4; r++) {
        const int row = m0 + wmb + mi * 16 + 4 * lg + r;
        out[(size_t)row * DMODEL + col] = acc[mi][ni][r] + bias;
      }
    }
}

// ---------------- launch ----------------

extern "C" void kernel_launch(void* const* d_in, const int* in_sizes, int n_in,
                              void* d_out, int out_size, void* d_ws, size_t ws_size,
                              hipStream_t stream) {
  const float* x  = (const float*)d_in[0];
  const float* Wq = (const float*)d_in[1];
  const float* Wk = (const float*)d_in[2];
  const float* Wv = (const float*)d_in[3];
  const float* Wo = (const float*)d_in[4];
  const float* bo = (const float*)d_in[5];
  float* out = (float*)d_out;

  char* ws = (char*)d_ws;
  uint16_t* Xb    = (uint16_t*)(ws);                      // 16 MiB [8192][1024]
  uint16_t* Ctx   = (uint16_t*)(ws);                      // aliases Xb (dead after QKV GEMMs)
  uint16_t* Wqkvt = (uint16_t*)(ws + (16u << 20));        //  6 MiB [3072][1024] (W^T)
  uint16_t* Wot   = (uint16_t*)(ws + (22u << 20));        //  2 MiB [1024][1024] (Wo^T)
  uint16_t* Qw    = (uint16_t*)(ws + (24u << 20));        // 16 MiB [64][2048][64]
  uint16_t* Kw    = (uint16_t*)(ws + (40u << 20));        // 16 MiB [64][2048][64]
  uint16_t* Vtw   = (uint16_t*)(ws + (56u << 20));        // 16 MiB [64][64][2048]
  (void)ws_size; (void)in_sizes; (void)n_in; (void)out_size;

  cvt_x_kernel<<<8192, 256, 0, stream>>>(x, Xb, 2097152);
  cvt_w_kernel<<<dim3(32, 32, 4), dim3(32, 8), 0, stream>>>(Wq, Wk, Wv, Wo, Wqkvt, Wot);
  gemm_qkv_fused<<<512, 512, 0, stream>>>(Xb, Wqkvt, Qw, Kw, Vtw);
  attn_kernel<<<1024, 256, 0, stream>>>(Qw, Kw, Vtw, Ctx);
  gemm_out_kernel<<<256, 512, 0, stream>>>(Ctx, Wot, bo, out);
}

// Round 16
// 151.198 us; speedup vs baseline: 1.1260x; 1.0410x over previous
//
#include <hip/hip_runtime.h>
#include <hip/hip_bf16.h>
#include <stdint.h>

#define TSEQ 2048
#define DMODEL 1024

typedef __attribute__((ext_vector_type(8))) short bf16x8;
typedef __attribute__((ext_vector_type(4))) float f32x4;
typedef __attribute__((ext_vector_type(16))) float f32x16;
typedef __attribute__((ext_vector_type(2))) int int2v;

union Frag { bf16x8 v; uint4 q; };

__device__ __forceinline__ uint16_t f2bfu(float f) {
  uint32_t u = __builtin_bit_cast(uint32_t, f);
  u += 0x7fffu + ((u >> 16) & 1u);
  return (uint16_t)(u >> 16);
}

__device__ __forceinline__ uint32_t cvtpk(float a, float b) {
  uint32_t r;
  asm("v_cvt_pk_bf16_f32 %0, %1, %2" : "=v"(r) : "v"(a), "v"(b));
  return r;
}

__device__ __forceinline__ void plane32swap(uint32_t& a, uint32_t& b) {
#if __has_builtin(__builtin_amdgcn_permlane32_swap)
  int2v r = __builtin_amdgcn_permlane32_swap((int)a, (int)b, false, false);
  a = (uint32_t)r[0];
  b = (uint32_t)r[1];
#else
  const uint32_t sa = (uint32_t)__shfl_xor((int)a, 32);
  const uint32_t sb = (uint32_t)__shfl_xor((int)b, 32);
  const bool hi = (threadIdx.x & 63) >= 32;
  const uint32_t na = hi ? sb : a;
  const uint32_t nb = hi ? b : sa;
  a = na;
  b = nb;
#endif
}

__device__ __forceinline__ float fexp2(float x) {
#if __has_builtin(__builtin_amdgcn_exp2f)
  return __builtin_amdgcn_exp2f(x);
#else
  return exp2f(x);
#endif
}

__device__ __forceinline__ void gload_lds16(const void* g, void* l) {
  __builtin_amdgcn_global_load_lds(
      (const __attribute__((address_space(1))) void*)g,
      (__attribute__((address_space(3))) void*)l, 16, 0, 0);
}

// ---------------- fused prep kernel ----------------
// blocks 0..8191: x fp32->bf16; blocks 8192..12287: W transpose+convert.

__global__ __launch_bounds__(256) void cvt_all_kernel(const float* __restrict__ x,
    const float* __restrict__ Wq, const float* __restrict__ Wk,
    const float* __restrict__ Wv, const float* __restrict__ Wo,
    uint16_t* __restrict__ xb, uint16_t* __restrict__ Wqkvt, uint16_t* __restrict__ Wot) {
  const int bid = blockIdx.x;
  const int tid = threadIdx.x;
  if (bid < 8192) {
    const int i = bid * 256 + tid;
    float4 v = ((const float4*)x)[i];
    ushort4 o;
    o.x = f2bfu(v.x); o.y = f2bfu(v.y); o.z = f2bfu(v.z); o.w = f2bfu(v.w);
    ((ushort4*)xb)[i] = o;
    return;
  }
  const int r = bid - 8192;
  const int wz = r >> 10;            // 0..3
  const int by = (r & 1023) >> 5;    // 0..31
  const int bx = r & 31;             // 0..31
  const float* src = (wz == 0) ? Wq : (wz == 1) ? Wk : (wz == 2) ? Wv : Wo;
  uint16_t* dst = (wz < 3) ? (Wqkvt + (size_t)wz * DMODEL * DMODEL) : Wot;
  const float wscale = (wz == 0) ? 0.125f * 1.4426950408889634f : 1.0f;
  __shared__ float tile[32][33];
  const int x0 = bx * 32, y0 = by * 32;
  const int tx = tid & 31, ty = tid >> 5;
  for (int ii = 0; ii < 4; ii++) {
    int i = ty + ii * 8;
    tile[i][tx] = src[(size_t)(y0 + i) * DMODEL + x0 + tx];
  }
  __syncthreads();
  for (int ii = 0; ii < 4; ii++) {
    int i = ty + ii * 8;
    dst[(size_t)(x0 + i) * DMODEL + y0 + tx] = f2bfu(tile[tx][i] * wscale);
  }
}

// ---- staging helpers ----
// full 256-row x 64-K tile (32KB): 4 x 512 threads
__device__ __forceinline__ void stage256(const char* Gb, int kb, char* ldsT, int tid) {
#pragma unroll
  for (int r = 0; r < 4; ++r) {
    const int u = tid + r * 512;
    const int row = u >> 3;
    const int sc = ((u & 7) * 16) ^ ((row & 7) << 4);
    gload_lds16(Gb + (size_t)row * 2048 + kb + sc, ldsT + u * 16);
  }
}
// one 128-row half-tile (16KB): 2 x 512 threads.  Caller offsets Gb/ldsT for h1.
__device__ __forceinline__ void stage_half256(const char* Gb, int kb, char* ldsT, int tid) {
#pragma unroll
  for (int r = 0; r < 2; ++r) {
    const int u = tid + r * 512;
    const int row = u >> 3;
    const int sc = ((u & 7) * 16) ^ ((row & 7) << 4);
    gload_lds16(Gb + (size_t)row * 2048 + kb + sc, ldsT + u * 16);
  }
}

// ======== 256x256 GEMM core v2: 4-phase fine-interleaved (m201-style) ========
// 8 waves (2M x 4N), per-wave 128x64, BK=64.  LDS 128KB (A,B dbuf 32KB each).
// Per tile: vmcnt(2) @top (prev tile landed, next A-h0 in flight), then 4
// quadrant phases (snake order, B frags held): each = {ds-read frags, issue
// one half-tile stage, setprio+16 MFMA+setprio, barrier}.

__device__ __forceinline__ void gemm256sq_core(const char* Ab, const char* Bb,
                                               char* lds,  // 131072 bytes
                                               f32x4 (&acc)[8][4]) {
  const int tid = threadIdx.x;
  const int lane = tid & 63;
  const int w = tid >> 6;
  const int lr = lane & 15, lg = lane >> 4;
  const int wmb = (w >> 2) * 128;  // 0,128
  const int wnb = (w & 3) * 64;    // 0,64,128,192
  char* const A0 = lds;
  char* const A1 = lds + 32768;
  char* const B0 = lds + 65536;
  char* const B1 = lds + 98304;

#pragma unroll
  for (int i = 0; i < 8; i++)
#pragma unroll
    for (int j = 0; j < 4; j++) acc[i][j] = (f32x4){0.f, 0.f, 0.f, 0.f};

  // prologue: full tile 0
  stage_half256(Ab, 0, A0, tid);
  stage_half256(Ab + (size_t)128 * 2048, 0, A0 + 16384, tid);
  stage_half256(Bb, 0, B0, tid);
  stage_half256(Bb + (size_t)128 * 2048, 0, B0 + 16384, tid);

  for (int t = 0; t < 16; ++t) {
    const char* At = (t & 1) ? A1 : A0;
    const char* Bt = (t & 1) ? B1 : B0;
    char* nA = (t & 1) ? A0 : A1;
    char* nB = (t & 1) ? B0 : B1;
    const int nkb = (t + 1) * 128;

    if (t + 1 < 16) {
      stage_half256(Ab, nkb, nA, tid);                    // A(t+1) h0
      asm volatile("s_waitcnt vmcnt(2)" ::: "memory");    // tile t fully landed
    } else {
      asm volatile("s_waitcnt vmcnt(0)" ::: "memory");
    }
    __builtin_amdgcn_s_barrier();                         // buffer t ready
    __builtin_amdgcn_sched_barrier(0);

    // ---- ph0: quadrant (mh0, nh0). loads: A mh0 (8) + B nh0 (4) ----
    Frag a0[4], a1[4];          // A frags for current mh, k-halves 0/1
    Frag b00[2], b01[2];        // B nh0
    Frag b10[2], b11[2];        // B nh1 (loaded ph1, held to ph2)
#pragma unroll
    for (int i = 0; i < 4; i++) {
      const int row = wmb + i * 16 + lr;
      const int swz = (row & 7) << 4;
      a0[i].q = *(const uint4*)(At + row * 128 + ((lg * 16) ^ swz));
      a1[i].q = *(const uint4*)(At + row * 128 + ((64 + lg * 16) ^ swz));
    }
#pragma unroll
    for (int i = 0; i < 2; i++) {
      const int row = wnb + i * 16 + lr;
      const int swz = (row & 7) << 4;
      b00[i].q = *(const uint4*)(Bt + row * 128 + ((lg * 16) ^ swz));
      b01[i].q = *(const uint4*)(Bt + row * 128 + ((64 + lg * 16) ^ swz));
    }
    if (t + 1 < 16) stage_half256(Ab + (size_t)128 * 2048, nkb, nA + 16384, tid);  // A h1
    __builtin_amdgcn_s_setprio(1);
#pragma unroll
    for (int i = 0; i < 4; i++)
#pragma unroll
      for (int j = 0; j < 2; j++) {
        acc[i][j] = __builtin_amdgcn_mfma_f32_16x16x32_bf16(a0[i].v, b00[j].v, acc[i][j], 0, 0, 0);
        acc[i][j] = __builtin_amdgcn_mfma_f32_16x16x32_bf16(a1[i].v, b01[j].v, acc[i][j], 0, 0, 0);
      }
    __builtin_amdgcn_s_setprio(0);
    __builtin_amdgcn_s_barrier();

    // ---- ph1: quadrant (mh0, nh1). loads: B nh1 (4); A reused ----
#pragma unroll
    for (int i = 0; i < 2; i++) {
      const int row = wnb + (2 + i) * 16 + lr;
      const int swz = (row & 7) << 4;
      b10[i].q = *(const uint4*)(Bt + row * 128 + ((lg * 16) ^ swz));
      b11[i].q = *(const uint4*)(Bt + row * 128 + ((64 + lg * 16) ^ swz));
    }
    if (t + 1 < 16) stage_half256(Bb, nkb, nB, tid);      // B(t+1) h0
    __builtin_amdgcn_s_setprio(1);
#pragma unroll
    for (int i = 0; i < 4; i++)
#pragma unroll
      for (int j = 0; j < 2; j++) {
        acc[i][2 + j] = __builtin_amdgcn_mfma_f32_16x16x32_bf16(a0[i].v, b10[j].v, acc[i][2 + j], 0, 0, 0);
        acc[i][2 + j] = __builtin_amdgcn_mfma_f32_16x16x32_bf16(a1[i].v, b11[j].v, acc[i][2 + j], 0, 0, 0);
      }
    __builtin_amdgcn_s_setprio(0);
    __builtin_amdgcn_s_barrier();

    // ---- ph2: quadrant (mh1, nh1). loads: A mh1 (8); B nh1 reused ----
#pragma unroll
    for (int i = 0; i < 4; i++) {
      const int row = wmb + (4 + i) * 16 + lr;
      const int swz = (row & 7) << 4;
      a0[i].q = *(const uint4*)(At + row * 128 + ((lg * 16) ^ swz));
      a1[i].q = *(const uint4*)(At + row * 128 + ((64 + lg * 16) ^ swz));
    }
    if (t + 1 < 16) stage_half256(Bb + (size_t)128 * 2048, nkb, nB + 16384, tid);  // B h1
    __builtin_amdgcn_s_setprio(1);
#pragma unroll
    for (int i = 0; i < 4; i++)
#pragma unroll
      for (int j = 0; j < 2; j++) {
        acc[4 + i][2 + j] = __builtin_amdgcn_mfma_f32_16x16x32_bf16(a0[i].v, b10[j].v, acc[4 + i][2 + j], 0, 0, 0);
        acc[4 + i][2 + j] = __builtin_amdgcn_mfma_f32_16x16x32_bf16(a1[i].v, b11[j].v, acc[4 + i][2 + j], 0, 0, 0);
      }
    __builtin_amdgcn_s_setprio(0);
    __builtin_amdgcn_s_barrier();

    // ---- ph3: quadrant (mh1, nh0). no loads (A mh1 + B nh0 in regs) ----
    __builtin_amdgcn_s_setprio(1);
#pragma unroll
    for (int i = 0; i < 4; i++)
#pragma unroll
      for (int j = 0; j < 2; j++) {
        acc[4 + i][j] = __builtin_amdgcn_mfma_f32_16x16x32_bf16(a0[i].v, b00[j].v, acc[4 + i][j], 0, 0, 0);
        acc[4 + i][j] = __builtin_amdgcn_mfma_f32_16x16x32_bf16(a1[i].v, b01[j].v, acc[4 + i][j], 0, 0, 0);
      }
    __builtin_amdgcn_s_setprio(0);
    __builtin_amdgcn_s_barrier();                         // buffer t fully consumed
  }
}

// ======== 256x128 GEMM core (round-9 verified; control group) ========

__device__ __forceinline__ void g8_stage_p1(const char* Ab, int kb, char* ldsA, int tid) {
#pragma unroll
  for (int r = 0; r < 3; ++r) {
    const int u = tid + r * 512;
    const int row = u >> 3;
    const int sc = ((u & 7) * 16) ^ ((row & 7) << 4);
    gload_lds16(Ab + (size_t)row * 2048 + kb + sc, ldsA + u * 16);
  }
}

__device__ __forceinline__ void g8_stage_p2(const char* Ab, const char* Bb, int kb,
                                            char* ldsA, char* ldsB, int tid) {
  {
    const int u = tid + 3 * 512;
    const int row = u >> 3;
    const int sc = ((u & 7) * 16) ^ ((row & 7) << 4);
    gload_lds16(Ab + (size_t)row * 2048 + kb + sc, ldsA + u * 16);
  }
#pragma unroll
  for (int r = 0; r < 2; ++r) {
    const int u = tid + r * 512;
    const int row = u >> 3;
    const int sc = ((u & 7) * 16) ^ ((row & 7) << 4);
    gload_lds16(Bb + (size_t)row * 2048 + kb + sc, ldsB + u * 16);
  }
}

__device__ __forceinline__ void gemm256x128_core(const char* Ab, const char* Bb,
                                                 char* lds,  // 98304 bytes
                                                 f32x4 (&acc)[4][4]) {
  const int tid = threadIdx.x;
  const int lane = tid & 63;
  const int w = tid >> 6;
  const int lr = lane & 15, lg = lane >> 4;
  const int wmb = (w >> 1) * 64;
  const int wnb = (w & 1) * 64;
  char* const A0 = lds;
  char* const A1 = lds + 32768;
  char* const B0 = lds + 65536;
  char* const B1 = lds + 81920;

#pragma unroll
  for (int i = 0; i < 4; i++)
#pragma unroll
    for (int j = 0; j < 4; j++) acc[i][j] = (f32x4){0.f, 0.f, 0.f, 0.f};

  g8_stage_p1(Ab, 0, A0, tid);
  g8_stage_p2(Ab, Bb, 0, A0, B0, tid);
  for (int t = 0; t < 16; ++t) {
    const char* At = (t & 1) ? A1 : A0;
    const char* Bt = (t & 1) ? B1 : B0;
    char* nA = (t & 1) ? A0 : A1;
    char* nB = (t & 1) ? B0 : B1;
    if (t + 1 < 16) {
      g8_stage_p1(Ab, (t + 1) * 128, nA, tid);
      asm volatile("s_waitcnt vmcnt(3)" ::: "memory");
    } else {
      asm volatile("s_waitcnt vmcnt(0)" ::: "memory");
    }
    __builtin_amdgcn_s_barrier();
    __builtin_amdgcn_sched_barrier(0);

    Frag bf0[4], bf1[4];
#pragma unroll
    for (int ni = 0; ni < 4; ni++) {
      const int row = wnb + ni * 16 + lr;
      const int swz = (row & 7) << 4;
      bf0[ni].q = *(const uint4*)(Bt + row * 128 + ((lg * 16) ^ swz));
      bf1[ni].q = *(const uint4*)(Bt + row * 128 + ((64 + lg * 16) ^ swz));
    }
    Frag pa0[2], pa1[2];
#pragma unroll
    for (int mi = 0; mi < 2; mi++) {
      const int row = wmb + mi * 16 + lr;
      const int swz = (row & 7) << 4;
      pa0[mi].q = *(const uint4*)(At + row * 128 + ((lg * 16) ^ swz));
      pa1[mi].q = *(const uint4*)(At + row * 128 + ((64 + lg * 16) ^ swz));
    }
    __builtin_amdgcn_s_setprio(1);
#pragma unroll
    for (int mi = 0; mi < 2; mi++)
#pragma unroll
      for (int ni = 0; ni < 4; ni++) {
        acc[mi][ni] = __builtin_amdgcn_mfma_f32_16x16x32_bf16(pa0[mi].v, bf0[ni].v,
                                                              acc[mi][ni], 0, 0, 0);
        acc[mi][ni] = __builtin_amdgcn_mfma_f32_16x16x32_bf16(pa1[mi].v, bf1[ni].v,
                                                              acc[mi][ni], 0, 0, 0);
      }
    __builtin_amdgcn_s_setprio(0);

    if (t + 1 < 16) g8_stage_p2(Ab, Bb, (t + 1) * 128, nA, nB, tid);
#pragma unroll
    for (int mi = 2; mi < 4; mi++) {
      const int row = wmb + mi * 16 + lr;
      const int swz = (row & 7) << 4;
      Frag qa0, qa1;
      qa0.q = *(const uint4*)(At + row * 128 + ((lg * 16) ^ swz));
      qa1.q = *(const uint4*)(At + row * 128 + ((64 + lg * 16) ^ swz));
      __builtin_amdgcn_s_setprio(1);
#pragma unroll
      for (int ni = 0; ni < 4; ni++) {
        acc[mi][ni] = __builtin_amdgcn_mfma_f32_16x16x32_bf16(qa0.v, bf0[ni].v,
                                                              acc[mi][ni], 0, 0, 0);
        acc[mi][ni] = __builtin_amdgcn_mfma_f32_16x16x32_bf16(qa1.v, bf1[ni].v,
                                                              acc[mi][ni], 0, 0, 0);
      }
      __builtin_amdgcn_s_setprio(0);
    }
    __builtin_amdgcn_s_barrier();
  }
}

// ---------------- fused QKV projection: 512 blocks = QK round + V round ----------

__global__ __launch_bounds__(512, 2) void gemm_qkv_fused(const uint16_t* __restrict__ Xb,
    const uint16_t* __restrict__ Wt, uint16_t* __restrict__ Qo,
    uint16_t* __restrict__ Ko, uint16_t* __restrict__ Vt) {
  __shared__ __align__(16) char lds[131072];
  const int tid = threadIdx.x, w = tid >> 6, lane = tid & 63;
  const int lr = lane & 15, lg = lane >> 4;

  if (blockIdx.x < 256) {
    // ---- QK path (new 4-phase core) ----
    const int m0 = (blockIdx.x & 31) * 256;
    const int n0 = (blockIdx.x >> 5) * 256;
    f32x4 acc[8][4];
    gemm256sq_core((const char*)Xb + (size_t)m0 * 2048, (const char*)Wt + (size_t)n0 * 2048,
                   lds, acc);
    const int wmb = (w >> 2) * 128, wnb = (w & 3) * 64;
#pragma unroll
    for (int mi = 0; mi < 8; mi++)
#pragma unroll
      for (int ni = 0; ni < 4; ni++) {
        const int col = n0 + wnb + ni * 16 + lr;
        const int p = col >> 10, c = col & 1023, h = c >> 6, d = c & 63;
#pragma unroll
        for (int r = 0; r < 4; r++) {
          const int row = m0 + wmb + mi * 16 + 4 * lg + r;
          const int bb = row >> 11, t = row & 2047;
          const int bh = bb * 16 + h;
          const uint16_t val = f2bfu(acc[mi][ni][r]);
          if (p == 0) Qo[((size_t)bh * TSEQ + t) * 64 + d] = val;
          else        Ko[((size_t)bh * TSEQ + t) * 64 + d] = val;
        }
      }
  } else {
    // ---- V path (round-9 core, unchanged) ----
    const int vb = blockIdx.x - 256;
    const int m0 = (vb & 31) * 256;
    const int n0 = (vb >> 5) * 128;
    const uint16_t* Wtv = Wt + (size_t)2048 * 1024;
    f32x4 acc[4][4];
    gemm256x128_core((const char*)Xb + (size_t)m0 * 2048, (const char*)Wtv + (size_t)n0 * 2048,
                     lds, acc);
    const int wmb = (w >> 1) * 64;
    char* vr = lds + (w & 1) * 33792;  // per-head region [64 d][528B]
#pragma unroll
    for (int mi = 0; mi < 4; mi++)
#pragma unroll
      for (int ni = 0; ni < 4; ni++) {
        const int d = ni * 16 + lr;
        const int tl = wmb + mi * 16 + 4 * lg;
        uint2 pr;
        pr.x = cvtpk(acc[mi][ni][0], acc[mi][ni][1]);
        pr.y = cvtpk(acc[mi][ni][2], acc[mi][ni][3]);
        *(uint2*)(vr + d * 528 + tl * 2) = pr;
      }
    __syncthreads();
    const int bb = m0 >> 11, t0 = m0 & 2047;
    const int h0 = n0 >> 6;
#pragma unroll
    for (int j = 0; j < 8; j++) {
      const int linear = (tid + j * 512) * 16;
      const int rg = linear >> 15;
      const int rem = linear & 32767;
      const int d = rem >> 9;
      const int toff = rem & 511;
      const uint4 val = *(const uint4*)(lds + rg * 33792 + d * 528 + toff);
      const int bh = bb * 16 + h0 + rg;
      *(uint4*)((char*)Vt + ((size_t)(bh * 64 + d) * TSEQ + t0) * 2 + toff) = val;
    }
  }
}

// ---------------- flash attention (round-12 config: best measured 58.4 us) -------

__device__ __forceinline__ void stage_kv(const char* Kb, const char* Vb, int kv0,
                                         char* kdst, char* vdst, int tid) {
  const int w1024 = (tid >> 6) * 1024;
#pragma unroll
  for (int i = 0; i < 2; i++) {
    const int o = i * 4096 + tid * 16;
    const int row = o >> 7;
    const int scol = (o & 127) ^ ((row & 7) << 4);
    gload_lds16(Kb + (size_t)(kv0 + row) * 128 + scol, kdst + i * 4096 + w1024);
    gload_lds16(Vb + (size_t)row * 4096 + kv0 * 2 + scol, vdst + i * 4096 + w1024);
  }
}

__global__ __launch_bounds__(256, 4) void attn_kernel(const uint16_t* __restrict__ Qw,
    const uint16_t* __restrict__ Kw, const uint16_t* __restrict__ Vtw,
    uint16_t* __restrict__ Ctx) {
  const int bid = blockIdx.x;
  const int c = bid & 255;
  const int rd = bid >> 8;
  const int g = c >> 6;
  int qt;
  if (rd == 0)      qt = 15 - g;
  else if (rd == 1) qt = 8 + g;
  else if (rd == 2) qt = 7 - g;
  else              qt = g;
  const int bh = c & 63;
  const int tid = threadIdx.x;
  const int w = tid >> 6, lane = tid & 63;
  const int lq = lane & 31;
  const int hi = lane >> 5;
  const int wq0 = qt * 128 + w * 32;

  const char* Qb = (const char*)Qw + (size_t)bh * TSEQ * 128;
  const char* Kb = (const char*)Kw + (size_t)bh * TSEQ * 128;
  const char* Vb = (const char*)Vtw + (size_t)bh * 64 * 4096;

  __shared__ __align__(16) char kbuf[2][8192];
  __shared__ __align__(16) char vbuf[2][8192];

  Frag qa[4];
#pragma unroll
  for (int kc = 0; kc < 4; kc++)
    qa[kc].q = *(const uint4*)(Qb + (size_t)(wq0 + lq) * 128 + kc * 32 + hi * 16);

  f32x16 o0 = 0.f, o1 = 0.f;
  float mrun = -1e30f, lrun = 0.f;

  const int nt = 2 * qt + 2;
  stage_kv(Kb, Vb, 0, kbuf[0], vbuf[0], tid);
  int cur = 0;
  for (int t = 0; t < nt; ++t) {
    const int kv0 = t * 64;
    if (t + 1 < nt) {
      stage_kv(Kb, Vb, kv0 + 64, kbuf[cur ^ 1], vbuf[cur ^ 1], tid);
      asm volatile("s_waitcnt vmcnt(4)" ::: "memory");
    } else {
      asm volatile("s_waitcnt vmcnt(0)" ::: "memory");
    }
    __builtin_amdgcn_s_barrier();
    __builtin_amdgcn_sched_barrier(0);

    if (kv0 <= wq0 + 31) {
      const char* Kt = kbuf[cur];
      const char* Vt = vbuf[cur];
      f32x16 s[2];
#pragma unroll
      for (int kvh = 0; kvh < 2; kvh++) {
        f32x16 acc = 0.f;
#pragma unroll
        for (int kc = 0; kc < 4; kc++) {
          const int row = kvh * 32 + lq;
          Frag kf;
          kf.q = *(const uint4*)(Kt + row * 128 + ((kc * 32 + hi * 16) ^ ((row & 7) << 4)));
          acc = __builtin_amdgcn_mfma_f32_32x32x16_bf16(kf.v, qa[kc].v, acc, 0, 0, 0);
        }
        s[kvh] = acc;
      }
      if (kv0 + 63 > wq0) {
        const int q_abs = wq0 + lq;
#pragma unroll
        for (int kvh = 0; kvh < 2; kvh++)
#pragma unroll
          for (int r = 0; r < 16; r++) {
            const int kv_abs = kv0 + kvh * 32 + (r & 3) + 8 * (r >> 2) + 4 * hi;
            if (kv_abs > q_abs) s[kvh][r] = -1e30f;
          }
      }
      float t8[8];
#pragma unroll
      for (int i = 0; i < 8; i++)
        t8[i] = fmaxf(fmaxf(s[0][2 * i], s[0][2 * i + 1]),
                      fmaxf(s[1][2 * i], s[1][2 * i + 1]));
      float t4a = fmaxf(t8[0], t8[1]), t4b = fmaxf(t8[2], t8[3]);
      float t4c = fmaxf(t8[4], t8[5]), t4d = fmaxf(t8[6], t8[7]);
      float mt = fmaxf(fmaxf(t4a, t4b), fmaxf(t4c, t4d));
      mt = fmaxf(mt, __shfl_xor(mt, 32));
      if (!__all(mt - mrun <= 8.0f)) {
        const float mnew = fmaxf(mrun, mt);
        const float corr = fexp2(mrun - mnew);
        mrun = mnew;
        lrun *= corr;
        o0 *= corr;
        o1 *= corr;
      }
#pragma unroll
      for (int kvh = 0; kvh < 2; kvh++)
#pragma unroll
        for (int r = 0; r < 16; r++) s[kvh][r] = fexp2(s[kvh][r] - mrun);
      float ps = 0.f;
#pragma unroll
      for (int kvh = 0; kvh < 2; kvh++)
#pragma unroll
        for (int r = 0; r < 16; r++) ps += s[kvh][r];
      ps += __shfl_xor(ps, 32);
      lrun += ps;
      uint32_t pk[2][8];
#pragma unroll
      for (int kvh = 0; kvh < 2; kvh++)
#pragma unroll
        for (int j = 0; j < 8; j++)
          pk[kvh][j] = cvtpk(s[kvh][2 * j], s[kvh][2 * j + 1]);
#pragma unroll
      for (int c16 = 0; c16 < 4; c16++) {
        const int kvh = c16 >> 1, cl = c16 & 1;
        uint32_t x0 = pk[kvh][4 * cl + 0], y0 = pk[kvh][4 * cl + 2];
        uint32_t x1 = pk[kvh][4 * cl + 1], y1 = pk[kvh][4 * cl + 3];
        plane32swap(x0, y0);
        plane32swap(x1, y1);
        Frag pb;
        pb.q.x = x0;
        pb.q.y = x1;
        pb.q.z = y0;
        pb.q.w = y1;
#pragma unroll
        for (int dblk = 0; dblk < 2; dblk++) {
          const int row = dblk * 32 + lq;
          Frag vf;
          vf.q = *(const uint4*)(Vt + row * 128 + ((c16 * 32 + hi * 16) ^ ((row & 7) << 4)));
          if (dblk == 0)
            o0 = __builtin_amdgcn_mfma_f32_32x32x16_bf16(vf.v, pb.v, o0, 0, 0, 0);
          else
            o1 = __builtin_amdgcn_mfma_f32_32x32x16_bf16(vf.v, pb.v, o1, 0, 0, 0);
        }
      }
    }
    __builtin_amdgcn_s_barrier();
    cur ^= 1;
  }

  const int bb = bh >> 4, hh = bh & 15;
  const float inv = 1.0f / lrun;
  const int q_abs = wq0 + lq;
  uint16_t* crow = Ctx + ((size_t)bb * TSEQ + q_abs) * DMODEL + hh * 64;
#pragma unroll
  for (int dblk = 0; dblk < 2; dblk++)
#pragma unroll
    for (int g2 = 0; g2 < 4; g2++) {
      const float a0 = (dblk ? o1[4 * g2 + 0] : o0[4 * g2 + 0]) * inv;
      const float a1 = (dblk ? o1[4 * g2 + 1] : o0[4 * g2 + 1]) * inv;
      const float a2 = (dblk ? o1[4 * g2 + 2] : o0[4 * g2 + 2]) * inv;
      const float a3 = (dblk ? o1[4 * g2 + 3] : o0[4 * g2 + 3]) * inv;
      uint2 st;
      st.x = cvtpk(a0, a1);
      st.y = cvtpk(a2, a3);
      *(uint2*)(crow + dblk * 32 + 8 * g2 + 4 * hi) = st;
    }
}

// ---------------- output projection + bias ----------------

__global__ __launch_bounds__(512, 2) void gemm_out_kernel(const uint16_t* __restrict__ Cb,
    const uint16_t* __restrict__ Wot, const float* __restrict__ bo,
    float* __restrict__ out) {
  __shared__ __align__(16) char lds[98304];
  const int m0 = (blockIdx.x & 31) * 256;
  const int n0 = (blockIdx.x >> 5) * 128;
  f32x4 acc[4][4];
  gemm256x128_core((const char*)Cb + (size_t)m0 * 2048, (const char*)Wot + (size_t)n0 * 2048,
                   lds, acc);

  const int tid = threadIdx.x, w = tid >> 6, lane = tid & 63;
  const int lr = lane & 15, lg = lane >> 4;
  const int wmb = (w >> 1) * 64, wnb = (w & 1) * 64;
#pragma unroll
  for (int mi = 0; mi < 4; mi++)
#pragma unroll
    for (int ni = 0; ni < 4; ni++) {
      const int col = n0 + wnb + ni * 16 + lr;
      const float bias = bo[col];
#pragma unroll
      for (int r = 0; r < 4; r++) {
        const int row = m0 + wmb + mi * 16 + 4 * lg + r;
        out[(size_t)row * DMODEL + col] = acc[mi][ni][r] + bias;
      }
    }
}

// ---------------- launch ----------------

extern "C" void kernel_launch(void* const* d_in, const int* in_sizes, int n_in,
                              void* d_out, int out_size, void* d_ws, size_t ws_size,
                              hipStream_t stream) {
  const float* x  = (const float*)d_in[0];
  const float* Wq = (const float*)d_in[1];
  const float* Wk = (const float*)d_in[2];
  const float* Wv = (const float*)d_in[3];
  const float* Wo = (const float*)d_in[4];
  const float* bo = (const float*)d_in[5];
  float* out = (float*)d_out;

  char* ws = (char*)d_ws;
  uint16_t* Xb    = (uint16_t*)(ws);                      // 16 MiB [8192][1024]
  uint16_t* Ctx   = (uint16_t*)(ws);                      // aliases Xb (dead after QKV GEMMs)
  uint16_t* Wqkvt = (uint16_t*)(ws + (16u << 20));        //  6 MiB [3072][1024] (W^T)
  uint16_t* Wot   = (uint16_t*)(ws + (22u << 20));        //  2 MiB [1024][1024] (Wo^T)
  uint16_t* Qw    = (uint16_t*)(ws + (24u << 20));        // 16 MiB [64][2048][64]
  uint16_t* Kw    = (uint16_t*)(ws + (40u << 20));        // 16 MiB [64][2048][64]
  uint16_t* Vtw   = (uint16_t*)(ws + (56u << 20));        // 16 MiB [64][64][2048]
  (void)ws_size; (void)in_sizes; (void)n_in; (void)out_size;

  cvt_all_kernel<<<12288, 256, 0, stream>>>(x, Wq, Wk, Wv, Wo, Xb, Wqkvt, Wot);
  gemm_qkv_fused<<<512, 512, 0, stream>>>(Xb, Wqkvt, Qw, Kw, Vtw);
  attn_kernel<<<1024, 256, 0, stream>>>(Qw, Kw, Vtw, Ctx);
  gemm_out_kernel<<<256, 512, 0, stream>>>(Ctx, Wot, bo, out);
}